// Round 3
// baseline (455.224 us; speedup 1.0000x reference)
//
#include <hip/hip_runtime.h>
#include <cmath>

// FullyConnectedTensorProductRescaleSwishGate — MI355X bf16-MFMA implementation.
//
// Decomposition (per row z):
//   A_s  (K=384) = [x0*y0 (256) | dot(x1,y1) (128)]
//       -> s1 (256 cols) via [C0*W0; C1*W1]^T, s2 (128 cols) via [C2*W2; C3*W3]^T
//   A_vi (K=512) = [x0*y1[i] | y0*x1_i | cross(x1,y1)_i],  i=0..2
//       -> v_i (128 cols) via [C4*W4; C5*W5; C6*W6]^T
//   out = [SILU_C*silu(s1*inv+b0) , (v*inv)*SIG_C*sigmoid(s2*inv+b1)]
//
// Weights are pre-scaled, bf16-converted, and transposed to [col][k] in d_ws
// (425,984 B) so B-fragments are contiguous 16B loads (L2-resident).

typedef __bf16 bf16_t;
typedef bf16_t bf16x8 __attribute__((ext_vector_type(8)));
typedef bf16_t bf16x4 __attribute__((ext_vector_type(4)));
typedef float  f32x4  __attribute__((ext_vector_type(4)));

#define BM 32
#define AS_STRIDE 392   // 384 + 8 pad (bf16 elems) -> b128 reads at bank floor
#define AV_STRIDE 520   // 512 + 8 pad

__global__ void prep_weights(const float* __restrict__ W0, const float* __restrict__ W1,
                             const float* __restrict__ W2, const float* __restrict__ W3,
                             const float* __restrict__ W4, const float* __restrict__ W5,
                             const float* __restrict__ W6,
                             bf16_t* __restrict__ WsT, bf16_t* __restrict__ WvT,
                             float c0, float c1, float c2, float c3,
                             float c4, float c5, float c6)
{
    int idx = blockIdx.x * 256 + threadIdx.x;
    if (idx < 384 * 384) {
        int col = idx / 384, k = idx % 384;     // WsT[col][k]
        float v;
        if (col < 256) {                        // s1 columns: C0*W0, C1*W1
            v = (k < 256) ? c0 * W0[k * 256 + col]
                          : c1 * W1[(k - 256) * 256 + col];
        } else {                                // s2 columns: C2*W2, C3*W3
            int c = col - 256;
            v = (k < 256) ? c2 * W2[k * 128 + c]
                          : c3 * W3[(k - 256) * 128 + c];
        }
        WsT[idx] = (bf16_t)v;
    } else if (idx < 384 * 384 + 128 * 512) {
        int j = idx - 384 * 384;
        int col = j / 512, k = j % 512;         // WvT[col][k]
        float v = (k < 256) ? c4 * W4[k * 128 + col]
                : (k < 384) ? c5 * W5[(k - 256) * 128 + col]
                            : c6 * W6[(k - 384) * 128 + col];
        WvT[j] = (bf16_t)v;
    }
}

__global__ __launch_bounds__(256) void tp_fused(
    const float* __restrict__ x, const float* __restrict__ y,
    const float* __restrict__ bias,
    const bf16_t* __restrict__ WsT, const bf16_t* __restrict__ WvT,
    float* __restrict__ out,
    float inv, float silu_c, float sig_c)
{
    __shared__ __attribute__((aligned(16))) bf16_t Abuf[BM * AV_STRIDE];
    __shared__ float ylds[BM][4];

    const int tid = threadIdx.x;
    const int l   = tid & 63;
    const int w   = tid >> 6;      // wave 0..3
    const int l15 = l & 15;
    const int lg  = l >> 4;        // lane group 0..3
    const int z0  = blockIdx.x * BM;

    if (tid < BM * 4) ylds[tid >> 2][tid & 3] = y[z0 * 4 + tid];
    __syncthreads();

    // ---------- build A_s in LDS ----------
    #pragma unroll
    for (int it = 0; it < 8; ++it) {            // k<256: x0*y0 (float4 coalesced)
        int f4 = tid + it * 256;
        int r = f4 >> 6, c4 = f4 & 63;
        float4 xv = *(const float4*)(x + (z0 + r) * 640 + c4 * 4);
        float y0 = ylds[r][0];
        bf16x4 o;
        o[0] = (bf16_t)(xv.x * y0); o[1] = (bf16_t)(xv.y * y0);
        o[2] = (bf16_t)(xv.z * y0); o[3] = (bf16_t)(xv.w * y0);
        *(bf16x4*)&Abuf[r * AS_STRIDE + c4 * 4] = o;
    }
    #pragma unroll
    for (int it = 0; it < 16; ++it) {           // k in [256,384): dot(x1,y1)
        int e = tid + it * 256;
        int r = e >> 7, u = e & 127;
        const float* xp = x + (z0 + r) * 640 + 256 + u * 3;
        float d = xp[0] * ylds[r][1] + xp[1] * ylds[r][2] + xp[2] * ylds[r][3];
        Abuf[r * AS_STRIDE + 256 + u] = (bf16_t)d;
    }
    __syncthreads();

    // ---------- phase 1: SG GEMM (each wave: 2 row-tiles x (4 S + 2 G) col-tiles) ----------
    f32x4 accS[2][4], accG[2][2];
    #pragma unroll
    for (int rt = 0; rt < 2; ++rt) {
        #pragma unroll
        for (int j = 0; j < 4; ++j) { f32x4 z = {0.f,0.f,0.f,0.f}; accS[rt][j] = z; }
        #pragma unroll
        for (int j = 0; j < 2; ++j) { f32x4 z = {0.f,0.f,0.f,0.f}; accG[rt][j] = z; }
    }

    {
        const int ab0 = (l15)      * AS_STRIDE + lg * 8;
        const int ab1 = (16 + l15) * AS_STRIDE + lg * 8;
        const bf16_t* bS[4]; const bf16_t* bG[2];
        #pragma unroll
        for (int j = 0; j < 4; ++j) bS[j] = WsT + ((w + 4 * j) * 16 + l15) * 384 + lg * 8;
        #pragma unroll
        for (int j = 0; j < 2; ++j) bG[j] = WsT + (256 + (w + 4 * j) * 16 + l15) * 384 + lg * 8;

        for (int kk = 0; kk < 12; ++kk) {
            bf16x8 a0 = *(const bf16x8*)&Abuf[ab0 + kk * 32];
            bf16x8 a1 = *(const bf16x8*)&Abuf[ab1 + kk * 32];
            #pragma unroll
            for (int j = 0; j < 4; ++j) {
                bf16x8 bb = *(const bf16x8*)(bS[j] + kk * 32);
                accS[0][j] = __builtin_amdgcn_mfma_f32_16x16x32_bf16(a0, bb, accS[0][j], 0, 0, 0);
                accS[1][j] = __builtin_amdgcn_mfma_f32_16x16x32_bf16(a1, bb, accS[1][j], 0, 0, 0);
            }
            #pragma unroll
            for (int j = 0; j < 2; ++j) {
                bf16x8 bb = *(const bf16x8*)(bG[j] + kk * 32);
                accG[0][j] = __builtin_amdgcn_mfma_f32_16x16x32_bf16(a0, bb, accG[0][j], 0, 0, 0);
                accG[1][j] = __builtin_amdgcn_mfma_f32_16x16x32_bf16(a1, bb, accG[1][j], 0, 0, 0);
            }
        }
    }

    // epilogue S: out_s = SILU_C * silu(acc*inv + b)
    #pragma unroll
    for (int rt = 0; rt < 2; ++rt) {
        #pragma unroll
        for (int j = 0; j < 4; ++j) {
            int col = (w + 4 * j) * 16 + l15;
            float bb = bias[col];
            #pragma unroll
            for (int rg = 0; rg < 4; ++rg) {
                int row = z0 + rt * 16 + lg * 4 + rg;   // D: row=(l>>4)*4+reg, col=l&15
                float v = accS[rt][j][rg] * inv + bb;
                out[row * 640 + col] = silu_c * v / (1.0f + __expf(-v));
            }
        }
    }
    // gates kept in registers — same (rt,j,rg,lane) mapping as the V tiles below
    float gate[2][2][4];
    #pragma unroll
    for (int rt = 0; rt < 2; ++rt) {
        #pragma unroll
        for (int j = 0; j < 2; ++j) {
            int col = (w + 4 * j) * 16 + l15;
            float bb = bias[256 + col];
            #pragma unroll
            for (int rg = 0; rg < 4; ++rg) {
                float v = accG[rt][j][rg] * inv + bb;
                gate[rt][j][rg] = sig_c / (1.0f + __expf(-v));
            }
        }
    }

    // ---------- phase 2: V GEMMs (i = 0..2), reuse Abuf ----------
    f32x4 accV[3][2][2];
    #pragma unroll
    for (int i = 0; i < 3; ++i)
        #pragma unroll
        for (int rt = 0; rt < 2; ++rt)
            #pragma unroll
            for (int j = 0; j < 2; ++j) { f32x4 z = {0.f,0.f,0.f,0.f}; accV[i][rt][j] = z; }

    const bf16_t* bV[2];
    #pragma unroll
    for (int j = 0; j < 2; ++j) bV[j] = WvT + ((w + 4 * j) * 16 + l15) * 512 + lg * 8;

    #pragma unroll
    for (int i = 0; i < 3; ++i) {               // fully unrolled: i, j1, j2 are literals
        const int j1 = (i + 1) % 3, j2 = (i + 2) % 3;
        __syncthreads();                        // all waves done reading Abuf
        #pragma unroll
        for (int it = 0; it < 8; ++it) {        // k<256: x0*y1[i]
            int f4 = tid + it * 256;
            int r = f4 >> 6, c4 = f4 & 63;
            float4 xv = *(const float4*)(x + (z0 + r) * 640 + c4 * 4);
            float yi = ylds[r][1 + i];
            bf16x4 o;
            o[0] = (bf16_t)(xv.x * yi); o[1] = (bf16_t)(xv.y * yi);
            o[2] = (bf16_t)(xv.z * yi); o[3] = (bf16_t)(xv.w * yi);
            *(bf16x4*)&Abuf[r * AV_STRIDE + c4 * 4] = o;
        }
        #pragma unroll
        for (int it = 0; it < 16; ++it) {       // k in [256,384): y0*x1_i ; [384,512): cross_i
            int e = tid + it * 256;
            int r = e >> 7, u = e & 127;
            const float* xp = x + (z0 + r) * 640 + 256 + u * 3;
            float a0 = xp[0], a1 = xp[1], a2 = xp[2];
            float ai  = (i  == 0) ? a0 : (i  == 1) ? a1 : a2;
            float aj1 = (j1 == 0) ? a0 : (j1 == 1) ? a1 : a2;
            float aj2 = (j2 == 0) ? a0 : (j2 == 1) ? a1 : a2;
            Abuf[r * AV_STRIDE + 256 + u] = (bf16_t)(ylds[r][0] * ai);
            Abuf[r * AV_STRIDE + 384 + u] = (bf16_t)(aj1 * ylds[r][1 + j2] - aj2 * ylds[r][1 + j1]);
        }
        __syncthreads();

        const int ab0 = (l15)      * AV_STRIDE + lg * 8;
        const int ab1 = (16 + l15) * AV_STRIDE + lg * 8;
        for (int kk = 0; kk < 16; ++kk) {
            bf16x8 a0 = *(const bf16x8*)&Abuf[ab0 + kk * 32];
            bf16x8 a1 = *(const bf16x8*)&Abuf[ab1 + kk * 32];
            #pragma unroll
            for (int j = 0; j < 2; ++j) {
                bf16x8 bb = *(const bf16x8*)(bV[j] + kk * 32);
                accV[i][0][j] = __builtin_amdgcn_mfma_f32_16x16x32_bf16(a0, bb, accV[i][0][j], 0, 0, 0);
                accV[i][1][j] = __builtin_amdgcn_mfma_f32_16x16x32_bf16(a1, bb, accV[i][1][j], 0, 0, 0);
            }
        }
    }

    // epilogue V: out_v[z, col, i] = v*inv*gate — contiguous 12B per lane
    #pragma unroll
    for (int rt = 0; rt < 2; ++rt) {
        #pragma unroll
        for (int j = 0; j < 2; ++j) {
            int col = (w + 4 * j) * 16 + l15;
            #pragma unroll
            for (int rg = 0; rg < 4; ++rg) {
                int row = z0 + rt * 16 + lg * 4 + rg;
                int base = row * 640 + 256 + col * 3;
                float g = gate[rt][j][rg] * inv;
                out[base + 0] = accV[0][rt][j][rg] * g;
                out[base + 1] = accV[1][rt][j][rg] * g;
                out[base + 2] = accV[2][rt][j][rg] * g;
            }
        }
    }
}

extern "C" void kernel_launch(void* const* d_in, const int* in_sizes, int n_in,
                              void* d_out, int out_size, void* d_ws, size_t ws_size,
                              hipStream_t stream)
{
    (void)n_in; (void)out_size; (void)ws_size;
    const float* x  = (const float*)d_in[0];
    const float* y  = (const float*)d_in[1];
    const float* W0 = (const float*)d_in[2];
    const float* W1 = (const float*)d_in[3];
    const float* W2 = (const float*)d_in[4];
    const float* W3 = (const float*)d_in[5];
    const float* W4 = (const float*)d_in[6];
    const float* W5 = (const float*)d_in[7];
    const float* W6 = (const float*)d_in[8];
    const float* b  = (const float*)d_in[9];
    float* out = (float*)d_out;

    const int n = in_sizes[0] / 640;            // 100000 (divisible by BM=32)

    bf16_t* WsT = (bf16_t*)d_ws;                // 384*384 bf16
    bf16_t* WvT = WsT + 384 * 384;              // 128*512 bf16 (total 425,984 B)

    // normalization constants (exact formulas from the reference)
    const double c0 = std::sqrt(256.0 * 256.0 / 384.0);
    const double c1 = std::sqrt(256.0 * 128.0 / 384.0) / std::sqrt(3.0);
    const double c2 = std::sqrt(128.0 * 256.0 / 384.0);
    const double c3 = std::sqrt(128.0 * 128.0 / 384.0) / std::sqrt(3.0);
    const double c4 = std::sqrt(3.0 * 128.0 * 256.0 / 512.0) / std::sqrt(3.0);  // = 8
    const double c5 = std::sqrt(3.0 * 128.0 * 128.0 / 512.0) / std::sqrt(3.0);  // = sqrt(32)
    const double c6 = std::sqrt(3.0 * 128.0 * 128.0 / 512.0) / std::sqrt(6.0);  // = 4
    const double inv = 1.0 / std::sqrt(2560.0);

    // second moments of silu/sigmoid under N(0,1): Simpson, matches 200-pt
    // Gauss-Hermite to ~1e-12 (deterministic, ~24k host exp calls)
    double m_silu = 0.0, m_sig = 0.0;
    {
        const int M = 24000;
        const double a = -12.0, h = 24.0 / M;
        for (int k = 0; k <= M; ++k) {
            double t = a + h * k;
            double wgt = (k == 0 || k == M) ? 1.0 : ((k & 1) ? 4.0 : 2.0);
            double sg = 1.0 / (1.0 + std::exp(-t));
            double phi = std::exp(-0.5 * t * t) * 0.3989422804014327;
            m_silu += wgt * (t * sg) * (t * sg) * phi;
            m_sig  += wgt * sg * sg * phi;
        }
        m_silu *= h / 3.0; m_sig *= h / 3.0;
    }
    const float silu_c = (float)(1.0 / std::sqrt(m_silu));
    const float sig_c  = (float)(1.0 / std::sqrt(m_sig));

    prep_weights<<<(384 * 384 + 128 * 512 + 255) / 256, 256, 0, stream>>>(
        W0, W1, W2, W3, W4, W5, W6, WsT, WvT,
        (float)c0, (float)c1, (float)c2, (float)c3, (float)c4, (float)c5, (float)c6);

    tp_fused<<<n / BM, 256, 0, stream>>>(x, y, b, WsT, WvT, out,
                                         (float)inv, silu_c, sig_c);
}

// Round 4
// 257.635 us; speedup vs baseline: 1.7669x; 1.7669x over previous
//
#include <hip/hip_runtime.h>
#include <cmath>

// FullyConnectedTensorProductRescaleSwishGate — MI355X bf16-MFMA, round 3.
//
// All y-dependences moved to the epilogue (y0, y1 are per-row scalars):
//   features A (K=768, built ONCE): [x0 (256) | dot=x1·y1 (128) | x1_0 | x1_1 | x1_2]
//   GEMM outputs per row: u0=x0@C0W0 (256), d1=dot@C1W1 (256),
//                         u2=x0@C2W2 (128), d3=dot@C3W3 (128), u4=x0@C4W4 (128),
//                         r_i=x1_i@C5W5 (128), q_i=x1_i@C6W6 (128)
//   s1 = y0*u0 + d1 ; s2 = y0*u2 + d3
//   v_i = y1_i*u4 + y0*r_i + y1_{j2}*q_{j1} - y1_{j1}*q_{j2}
// One barrier per block; x read exactly once; A in LDS with XOR bank swizzle.

typedef __bf16 bf16_t;
typedef bf16_t bf16x8 __attribute__((ext_vector_type(8)));
typedef bf16_t bf16x4 __attribute__((ext_vector_type(4)));
typedef float  f32x4  __attribute__((ext_vector_type(4)));

#define BM 32
#define KP 768          // row stride (elems) = 1536 B = 12*128 B -> clean XOR swizzle

// weight group offsets in d_ws (bf16 elements), all stored [col][k], pre-scaled
#define WU0 0           // 256 x 256
#define WD1 65536       // 256 x 128
#define WU2 98304       // 128 x 256
#define WD3 131072      // 128 x 128
#define WU4 147456      // 128 x 256
#define WR  180224      // 128 x 128
#define WQ  196608      // 128 x 128
#define WTOT 212992

#define MFMA(acc, av, bv) acc = __builtin_amdgcn_mfma_f32_16x16x32_bf16(av, bv, acc, 0, 0, 0)

__global__ void prep_weights(const float* __restrict__ W0, const float* __restrict__ W1,
                             const float* __restrict__ W2, const float* __restrict__ W3,
                             const float* __restrict__ W4, const float* __restrict__ W5,
                             const float* __restrict__ W6, bf16_t* __restrict__ WT,
                             float c0, float c1, float c2, float c3,
                             float c4, float c5, float c6)
{
    int idx = blockIdx.x * 256 + threadIdx.x;
    if (idx >= WTOT) return;
    float v;
    if (idx < WD1)      { int c = idx >> 8, k = idx & 255;                    v = c0 * W0[k * 256 + c]; }
    else if (idx < WU2) { int j = idx - WD1; int c = j >> 7, k = j & 127;     v = c1 * W1[k * 256 + c]; }
    else if (idx < WD3) { int j = idx - WU2; int c = j >> 8, k = j & 255;     v = c2 * W2[k * 128 + c]; }
    else if (idx < WU4) { int j = idx - WD3; int c = j >> 7, k = j & 127;     v = c3 * W3[k * 128 + c]; }
    else if (idx < WR)  { int j = idx - WU4; int c = j >> 8, k = j & 255;     v = c4 * W4[k * 128 + c]; }
    else if (idx < WQ)  { int j = idx - WR;  int c = j >> 7, k = j & 127;     v = c5 * W5[k * 128 + c]; }
    else                { int j = idx - WQ;  int c = j >> 7, k = j & 127;     v = c6 * W6[k * 128 + c]; }
    WT[idx] = (bf16_t)v;
}

__global__ __launch_bounds__(512) void tp_fused(
    const float* __restrict__ x, const float* __restrict__ y,
    const float* __restrict__ bias, const bf16_t* __restrict__ WT,
    float* __restrict__ out, float inv, float silu_c, float sig_c)
{
    __shared__ __attribute__((aligned(16))) bf16_t A[BM * KP];
    __shared__ float ylds[BM][4];

    const int tid = threadIdx.x;
    const int l   = tid & 63;
    const int w   = tid >> 6;          // wave 0..7
    const int l15 = l & 15;
    const int lg  = l >> 4;            // lane group 0..3
    const int z0  = blockIdx.x * BM;

    if (tid < BM * 4) ylds[tid >> 2][tid & 3] = y[z0 * 4 + tid];

    // ---- feature build (one pass; x read exactly once) ----
    #pragma unroll
    for (int it = 0; it < 4; ++it) {                 // k<256: x0 raw -> bf16
        int f4 = tid + it * 512;
        int r = f4 >> 6, c4 = f4 & 63;
        float4 xv = *(const float4*)(x + (z0 + r) * 640 + c4 * 4);
        bf16x4 o;
        o[0] = (bf16_t)xv.x; o[1] = (bf16_t)xv.y; o[2] = (bf16_t)xv.z; o[3] = (bf16_t)xv.w;
        *(bf16x4*)&A[r * KP + ((c4 * 4) ^ ((r & 7) << 3))] = o;
    }
    #pragma unroll
    for (int it = 0; it < 8; ++it) {                 // dot + x1_0/1/2 de-interleave
        int e = tid + it * 512;
        int r = e >> 7, u = e & 127;
        const float* xp = x + (z0 + r) * 640 + 256 + u * 3;
        float a0 = xp[0], a1 = xp[1], a2 = xp[2];
        float4 yv = *(const float4*)(y + (z0 + r) * 4);   // broadcast within row
        int sw = (r & 7) << 3, base = r * KP;
        A[base + ((256 + u) ^ sw)] = (bf16_t)(a0 * yv.y + a1 * yv.z + a2 * yv.w);
        A[base + ((384 + u) ^ sw)] = (bf16_t)a0;
        A[base + ((512 + u) ^ sw)] = (bf16_t)a1;
        A[base + ((640 + u) ^ sw)] = (bf16_t)a2;
    }
    __syncthreads();

    const int asw    = (l15 & 7) << 3;               // XOR swizzle (same for row, row+16)
    const int a0base = l15 * KP;
    const int a1base = (16 + l15) * KP;
    const int klane  = lg * 8;

    // ---- S phase: s1 columns. wave w owns col-tiles {w, w+8} of 16 ----
    {
        f32x4 sU[2][2], sD[2][2];
        #pragma unroll
        for (int a = 0; a < 2; ++a)
            #pragma unroll
            for (int b = 0; b < 2; ++b) { f32x4 z = {0.f,0.f,0.f,0.f}; sU[a][b] = z; sD[a][b] = z; }

        const bf16_t* b0p = WT + WU0 + ((w    ) * 16 + l15) * 256 + klane;
        const bf16_t* b1p = WT + WU0 + ((w + 8) * 16 + l15) * 256 + klane;
        const bf16_t* d0p = WT + WD1 + ((w    ) * 16 + l15) * 128 + klane;
        const bf16_t* d1p = WT + WD1 + ((w + 8) * 16 + l15) * 128 + klane;

        #pragma unroll
        for (int kk = 0; kk < 8; ++kk) {             // u0 over K=256
            bf16x8 a0 = *(const bf16x8*)&A[a0base + ((kk * 32 + klane) ^ asw)];
            bf16x8 a1 = *(const bf16x8*)&A[a1base + ((kk * 32 + klane) ^ asw)];
            bf16x8 bb = *(const bf16x8*)(b0p + kk * 32);
            MFMA(sU[0][0], a0, bb); MFMA(sU[0][1], a1, bb);
            bb = *(const bf16x8*)(b1p + kk * 32);
            MFMA(sU[1][0], a0, bb); MFMA(sU[1][1], a1, bb);
        }
        #pragma unroll
        for (int kk = 0; kk < 4; ++kk) {             // d1 over K=128 (dot block)
            bf16x8 a0 = *(const bf16x8*)&A[a0base + ((256 + kk * 32 + klane) ^ asw)];
            bf16x8 a1 = *(const bf16x8*)&A[a1base + ((256 + kk * 32 + klane) ^ asw)];
            bf16x8 bb = *(const bf16x8*)(d0p + kk * 32);
            MFMA(sD[0][0], a0, bb); MFMA(sD[0][1], a1, bb);
            bb = *(const bf16x8*)(d1p + kk * 32);
            MFMA(sD[1][0], a0, bb); MFMA(sD[1][1], a1, bb);
        }
        #pragma unroll
        for (int cs = 0; cs < 2; ++cs) {             // epilogue: silu
            int col = (w + 8 * cs) * 16 + l15;
            float bv = bias[col];
            #pragma unroll
            for (int rt = 0; rt < 2; ++rt)
                #pragma unroll
                for (int rg = 0; rg < 4; ++rg) {
                    int lr = rt * 16 + lg * 4 + rg;
                    float sv = (ylds[lr][0] * sU[cs][rt][rg] + sD[cs][rt][rg]) * inv + bv;
                    out[(z0 + lr) * 640 + col] = silu_c * sv / (1.0f + __expf(-sv));
                }
        }
    }

    // ---- V phase: wave w owns v-family col-tile w (16 of 128 cols) ----
    {
        f32x4 vU2[2], vU4[2], vD3[2], vR[3][2], vQ[3][2];
        #pragma unroll
        for (int rt = 0; rt < 2; ++rt) {
            f32x4 z = {0.f,0.f,0.f,0.f};
            vU2[rt] = z; vU4[rt] = z; vD3[rt] = z;
            #pragma unroll
            for (int i = 0; i < 3; ++i) { vR[i][rt] = z; vQ[i][rt] = z; }
        }
        const bf16_t* pu2 = WT + WU2 + (w * 16 + l15) * 256 + klane;
        const bf16_t* pu4 = WT + WU4 + (w * 16 + l15) * 256 + klane;
        const bf16_t* pd3 = WT + WD3 + (w * 16 + l15) * 128 + klane;
        const bf16_t* pr  = WT + WR  + (w * 16 + l15) * 128 + klane;
        const bf16_t* pq  = WT + WQ  + (w * 16 + l15) * 128 + klane;

        #pragma unroll
        for (int kk = 0; kk < 8; ++kk) {             // u2 & u4 share A-frags (x0 block)
            bf16x8 a0 = *(const bf16x8*)&A[a0base + ((kk * 32 + klane) ^ asw)];
            bf16x8 a1 = *(const bf16x8*)&A[a1base + ((kk * 32 + klane) ^ asw)];
            bf16x8 bb = *(const bf16x8*)(pu2 + kk * 32);
            MFMA(vU2[0], a0, bb); MFMA(vU2[1], a1, bb);
            bb = *(const bf16x8*)(pu4 + kk * 32);
            MFMA(vU4[0], a0, bb); MFMA(vU4[1], a1, bb);
        }
        #pragma unroll
        for (int kk = 0; kk < 4; ++kk) {             // d3 (dot block)
            bf16x8 a0 = *(const bf16x8*)&A[a0base + ((256 + kk * 32 + klane) ^ asw)];
            bf16x8 a1 = *(const bf16x8*)&A[a1base + ((256 + kk * 32 + klane) ^ asw)];
            bf16x8 bb = *(const bf16x8*)(pd3 + kk * 32);
            MFMA(vD3[0], a0, bb); MFMA(vD3[1], a1, bb);
        }
        #pragma unroll
        for (int kk = 0; kk < 4; ++kk) {             // r_i & q_i: W5/W6 frags shared over i
            bf16x8 brr = *(const bf16x8*)(pr + kk * 32);
            bf16x8 bqq = *(const bf16x8*)(pq + kk * 32);
            #pragma unroll
            for (int i = 0; i < 3; ++i) {
                int kb = 384 + i * 128 + kk * 32;
                bf16x8 a0 = *(const bf16x8*)&A[a0base + ((kb + klane) ^ asw)];
                bf16x8 a1 = *(const bf16x8*)&A[a1base + ((kb + klane) ^ asw)];
                MFMA(vR[i][0], a0, brr); MFMA(vR[i][1], a1, brr);
                MFMA(vQ[i][0], a0, bqq); MFMA(vQ[i][1], a1, bqq);
            }
        }

        // epilogue: gate + cross recombination + store (12B/lane contiguous)
        int col = w * 16 + l15;
        float b2v = bias[256 + col];
        #pragma unroll
        for (int rt = 0; rt < 2; ++rt)
            #pragma unroll
            for (int rg = 0; rg < 4; ++rg) {
                int lr = rt * 16 + lg * 4 + rg;
                float y0 = ylds[lr][0], ya = ylds[lr][1], yb = ylds[lr][2], yc = ylds[lr][3];
                float sv = (y0 * vU2[rt][rg] + vD3[rt][rg]) * inv + b2v;
                float g  = sig_c * inv / (1.0f + __expf(-sv));
                float u4v = vU4[rt][rg];
                float v0 = ya * u4v + y0 * vR[0][rt][rg] + yc * vQ[1][rt][rg] - yb * vQ[2][rt][rg];
                float v1 = yb * u4v + y0 * vR[1][rt][rg] + ya * vQ[2][rt][rg] - yc * vQ[0][rt][rg];
                float v2 = yc * u4v + y0 * vR[2][rt][rg] + yb * vQ[0][rt][rg] - ya * vQ[1][rt][rg];
                int base = (z0 + lr) * 640 + 256 + col * 3;
                out[base + 0] = v0 * g;
                out[base + 1] = v1 * g;
                out[base + 2] = v2 * g;
            }
    }
}

extern "C" void kernel_launch(void* const* d_in, const int* in_sizes, int n_in,
                              void* d_out, int out_size, void* d_ws, size_t ws_size,
                              hipStream_t stream)
{
    (void)n_in; (void)out_size; (void)ws_size;
    const float* x  = (const float*)d_in[0];
    const float* y  = (const float*)d_in[1];
    const float* W0 = (const float*)d_in[2];
    const float* W1 = (const float*)d_in[3];
    const float* W2 = (const float*)d_in[4];
    const float* W3 = (const float*)d_in[5];
    const float* W4 = (const float*)d_in[6];
    const float* W5 = (const float*)d_in[7];
    const float* W6 = (const float*)d_in[8];
    const float* b  = (const float*)d_in[9];
    float* out = (float*)d_out;

    const int n = in_sizes[0] / 640;                 // 100000, divisible by BM=32

    bf16_t* WT = (bf16_t*)d_ws;                      // 212,992 bf16 = 425,984 B

    const double c0 = std::sqrt(256.0 * 256.0 / 384.0);
    const double c1 = std::sqrt(256.0 * 128.0 / 384.0) / std::sqrt(3.0);
    const double c2 = std::sqrt(128.0 * 256.0 / 384.0);
    const double c3 = std::sqrt(128.0 * 128.0 / 384.0) / std::sqrt(3.0);
    const double c4 = std::sqrt(3.0 * 128.0 * 256.0 / 512.0) / std::sqrt(3.0);
    const double c5 = std::sqrt(3.0 * 128.0 * 128.0 / 512.0) / std::sqrt(3.0);
    const double c6 = std::sqrt(3.0 * 128.0 * 128.0 / 512.0) / std::sqrt(6.0);
    const double inv = 1.0 / std::sqrt(2560.0);

    // second moments of silu/sigmoid under N(0,1) via Simpson (matches hermgauss)
    double m_silu = 0.0, m_sig = 0.0;
    {
        const int M = 24000;
        const double a = -12.0, h = 24.0 / M;
        for (int k = 0; k <= M; ++k) {
            double t = a + h * k;
            double wgt = (k == 0 || k == M) ? 1.0 : ((k & 1) ? 4.0 : 2.0);
            double sg = 1.0 / (1.0 + std::exp(-t));
            double phi = std::exp(-0.5 * t * t) * 0.3989422804014327;
            m_silu += wgt * (t * sg) * (t * sg) * phi;
            m_sig  += wgt * sg * sg * phi;
        }
        m_silu *= h / 3.0; m_sig *= h / 3.0;
    }
    const float silu_c = (float)(1.0 / std::sqrt(m_silu));
    const float sig_c  = (float)(1.0 / std::sqrt(m_sig));

    prep_weights<<<(WTOT + 255) / 256, 256, 0, stream>>>(
        W0, W1, W2, W3, W4, W5, W6, WT,
        (float)c0, (float)c1, (float)c2, (float)c3, (float)c4, (float)c5, (float)c6);

    tp_fused<<<n / BM, 512, 0, stream>>>(x, y, b, WT, out,
                                         (float)inv, silu_c, sig_c);
}